// Round 4
// baseline (213.806 us; speedup 1.0000x reference)
//
#include <hip/hip_runtime.h>

// CrossAttention with LoRA (folded). B=16, C=64, hw=4096, L=77, COND=768, HEADS=8, dh=8.
// Round 5: kvproj3 — 8 rows per wave (was 1). Each wave's 196KB weight stream is now
// amortized over 8 rows (8x less L1/L2 traffic); x loads are block-uniform -> scalar
// s_load broadcasts; 8 independent acc chains give ILP. megattn/prep untouched.
// Pipeline: prep_weights -> kvproj3 -> megattn  (3 launches).

#define HW   4096
#define CHN  64
#define LSEQ 77
#define CD   768
#define NB   16

// workspace float offsets
#define OFF_WQ 0
#define OFF_WK 4096
#define OFF_WV 53248
#define OFF_WO 102400
#define OFF_K  106496
#define OFF_V  185344

#define QF 0.51011784563163f  // SCALE * log2(e) = 8^-0.5 * 1.442695...

__global__ __launch_bounds__(256) void prep_weights(
    const float* __restrict__ Wq, const float* __restrict__ Aq, const float* __restrict__ Bq,
    const float* __restrict__ Wk, const float* __restrict__ Ak, const float* __restrict__ Bk,
    const float* __restrict__ Wv, const float* __restrict__ Av, const float* __restrict__ Bv,
    const float* __restrict__ Wo, const float* __restrict__ Ao, const float* __restrict__ Bo,
    float* __restrict__ ws) {
  int idx = blockIdx.x * 256 + threadIdx.x;   // 416*256 = 106496 exact
  const float *W, *A, *Bm;
  float* out;
  int in_d, local;
  float scale = 1.0f;
  if (idx < 4096)        { W = Wq; A = Aq; Bm = Bq; out = ws + OFF_WQ; in_d = 64;  local = idx; scale = QF; }
  else if (idx < 53248)  { W = Wk; A = Ak; Bm = Bk; out = ws + OFF_WK; in_d = 768; local = idx - 4096; }
  else if (idx < 102400) { W = Wv; A = Av; Bm = Bv; out = ws + OFF_WV; in_d = 768; local = idx - 53248; }
  else                   { W = Wo; A = Ao; Bm = Bo; out = ws + OFF_WO; in_d = 64;  local = idx - 102400; }
  int co = local & 63;
  int c  = local >> 6;
  float val = W[co * in_d + c];
  #pragma unroll
  for (int r = 0; r < 8; r++) val += Bm[co * 8 + r] * A[r * in_d + c];
  out[local] = val * scale;   // local == c*64+co : W_eff^T [in][out]
}

// K/V projection: 1 wave per block, lane = co, 8 rows per wave.
// grid (154, 2 kv): 154*8 = 1232 = 16*77 rows exact.
// Weights wT[c*64+co]: 256B coalesced loads, each serving 8 rows (8x traffic cut).
// x: block-uniform addresses -> scalar s_load broadcasts (1 load per 64 lanes).
__global__ __launch_bounds__(64) void kvproj3(
    const float* __restrict__ cond,  // [1232][768]
    const float* __restrict__ wkT,   // [768][64]
    const float* __restrict__ wvT,
    const float* __restrict__ bk, const float* __restrict__ bv,
    float* __restrict__ kbuf,        // [1232][64]
    float* __restrict__ vbuf) {
  int kv = blockIdx.y;
  int co = threadIdx.x;            // 0..63
  int r0 = blockIdx.x * 8;
  const float* wT = kv ? wvT : wkT;
  float bias = (kv ? bv : bk)[co];
  float acc[8];
  #pragma unroll
  for (int j = 0; j < 8; j++) acc[j] = bias;
  const float* x0 = cond + r0 * CD;
  #pragma unroll 4
  for (int c4 = 0; c4 < CD / 4; c4++) {
    float w0 = wT[(4 * c4 + 0) * 64 + co];
    float w1 = wT[(4 * c4 + 1) * 64 + co];
    float w2 = wT[(4 * c4 + 2) * 64 + co];
    float w3 = wT[(4 * c4 + 3) * 64 + co];
    #pragma unroll
    for (int j = 0; j < 8; j++) {
      float4 xv = *(const float4*)(x0 + j * CD + 4 * c4);   // uniform -> s_load_dwordx4
      acc[j] = fmaf(xv.x, w0, acc[j]);
      acc[j] = fmaf(xv.y, w1, acc[j]);
      acc[j] = fmaf(xv.z, w2, acc[j]);
      acc[j] = fmaf(xv.w, w3, acc[j]);
    }
  }
  float* ob = (kv ? vbuf : kbuf) + r0 * 64 + co;
  #pragma unroll
  for (int j = 0; j < 8; j++) ob[j * 64] = acc[j];
}

// Fused q-proj + attention + o-proj (round-0 geometry: 256 threads, 4 px/thread).
// grid (32 ptiles of 128, 16 b), block 256. h = t>>5, pl = t&31, 4 pixels/thread.
// qT never materialized; ao round-trips through LDS (stride-65 padding, 2-way conflict = free).
// Logits bounded => single-pass softmax with exp2 (wqT pre-scaled by SCALE*log2e).
__global__ __launch_bounds__(256, 2) void megattn(
    const float* __restrict__ z,     // [16][64][4096]
    const float* __restrict__ wqT,   // [64][64] (pre-scaled by QF)
    const float* __restrict__ bq,
    const float* __restrict__ kbuf,  // [16][77][64]
    const float* __restrict__ vbuf,
    const float* __restrict__ woT,   // [64][64]
    const float* __restrict__ bo,
    float* __restrict__ out) {       // [16][64][4096]
  __shared__ float smem[LSEQ * 64 * 2];   // 9856 floats: k|v ; later reused as ao[128][65]
  int b  = blockIdx.y;
  int p0 = blockIdx.x * 128;
  int t  = threadIdx.x;
  int h  = t >> 5;
  int pl = t & 31;

  float* ks = smem;
  float* vs = smem + LSEQ * 64;
  {
    const float4* ksrc = (const float4*)(kbuf + b * LSEQ * 64);
    const float4* vsrc = (const float4*)(vbuf + b * LSEQ * 64);
    float4* kd = (float4*)ks;
    float4* vd = (float4*)vs;
    for (int i = t; i < LSEQ * 16; i += 256) { kd[i] = ksrc[i]; vd[i] = vsrc[i]; }
  }

  // ---- Q phase: q[p][8h..8h+7] for p = p0 + pl + 32*i, i<4 (runs before the barrier) ----
  float qr[4][8];
  {
    const float4 b0 = *(const float4*)(bq + 8 * h);
    const float4 b1 = *(const float4*)(bq + 8 * h + 4);
    #pragma unroll
    for (int i = 0; i < 4; i++) {
      qr[i][0] = b0.x * QF; qr[i][1] = b0.y * QF; qr[i][2] = b0.z * QF; qr[i][3] = b0.w * QF;
      qr[i][4] = b1.x * QF; qr[i][5] = b1.y * QF; qr[i][6] = b1.z * QF; qr[i][7] = b1.w * QF;
    }
  }
  const float* zb = z + b * (CHN * HW) + p0 + pl;
  #pragma unroll 4
  for (int c = 0; c < 64; c++) {
    float4 w0 = *(const float4*)(wqT + c * 64 + 8 * h);
    float4 w1 = *(const float4*)(wqT + c * 64 + 8 * h + 4);
    float zv[4];
    #pragma unroll
    for (int i = 0; i < 4; i++) zv[i] = zb[c * HW + 32 * i];
    #pragma unroll
    for (int i = 0; i < 4; i++) {
      qr[i][0] = fmaf(zv[i], w0.x, qr[i][0]);
      qr[i][1] = fmaf(zv[i], w0.y, qr[i][1]);
      qr[i][2] = fmaf(zv[i], w0.z, qr[i][2]);
      qr[i][3] = fmaf(zv[i], w0.w, qr[i][3]);
      qr[i][4] = fmaf(zv[i], w1.x, qr[i][4]);
      qr[i][5] = fmaf(zv[i], w1.y, qr[i][5]);
      qr[i][6] = fmaf(zv[i], w1.z, qr[i][6]);
      qr[i][7] = fmaf(zv[i], w1.w, qr[i][7]);
    }
  }
  __syncthreads();

  // ---- Attention phase ----
  float acc[4][8];
  float li[4];
  #pragma unroll
  for (int i = 0; i < 4; i++) {
    li[i] = 0.f;
    #pragma unroll
    for (int d = 0; d < 8; d++) acc[i][d] = 0.f;
  }
  #pragma unroll 2
  for (int j = 0; j < LSEQ; j++) {
    float4 k0 = *(const float4*)(ks + j * 64 + 8 * h);
    float4 k1 = *(const float4*)(ks + j * 64 + 8 * h + 4);
    float4 v0 = *(const float4*)(vs + j * 64 + 8 * h);
    float4 v1 = *(const float4*)(vs + j * 64 + 8 * h + 4);
    #pragma unroll
    for (int i = 0; i < 4; i++) {
      float s = qr[i][0] * k0.x;
      s = fmaf(qr[i][1], k0.y, s);
      s = fmaf(qr[i][2], k0.z, s);
      s = fmaf(qr[i][3], k0.w, s);
      s = fmaf(qr[i][4], k1.x, s);
      s = fmaf(qr[i][5], k1.y, s);
      s = fmaf(qr[i][6], k1.z, s);
      s = fmaf(qr[i][7], k1.w, s);
      float e = __builtin_amdgcn_exp2f(s);
      li[i] += e;
      acc[i][0] = fmaf(e, v0.x, acc[i][0]);
      acc[i][1] = fmaf(e, v0.y, acc[i][1]);
      acc[i][2] = fmaf(e, v0.z, acc[i][2]);
      acc[i][3] = fmaf(e, v0.w, acc[i][3]);
      acc[i][4] = fmaf(e, v1.x, acc[i][4]);
      acc[i][5] = fmaf(e, v1.y, acc[i][5]);
      acc[i][6] = fmaf(e, v1.z, acc[i][6]);
      acc[i][7] = fmaf(e, v1.w, acc[i][7]);
    }
  }
  __syncthreads();   // all k/v reads done; smem reusable

  // ---- ao -> LDS, layout [128][65] (stride 65: 2 lanes/bank = free) ----
  float* ao = smem;
  #pragma unroll
  for (int i = 0; i < 4; i++) {
    float inv = 1.0f / li[i];
    int p = pl + 32 * i;
    #pragma unroll
    for (int d = 0; d < 8; d++) ao[p * 65 + 8 * h + d] = acc[i][d] * inv;
  }
  __syncthreads();

  // ---- O phase: out[p][co] = ao[p] . woT[:,co] + bo ----
  int q2 = t & 127;
  int chalf = __builtin_amdgcn_readfirstlane((t >> 7) & 1);  // wave-uniform -> scalar weight loads
  float acc2[32];
  #pragma unroll
  for (int j2 = 0; j2 < 32; j2++) acc2[j2] = bo[chalf * 32 + j2];
  const float* aor = ao + q2 * 65;
  #pragma unroll 4
  for (int c = 0; c < 64; c++) {
    float xv = aor[c];
    const float* wr = woT + c * 64 + chalf * 32;
    #pragma unroll
    for (int j2 = 0; j2 < 32; j2++) acc2[j2] = fmaf(xv, wr[j2], acc2[j2]);
  }
  float* ob = out + b * (CHN * HW) + p0 + q2;
  #pragma unroll
  for (int j2 = 0; j2 < 32; j2++) ob[(chalf * 32 + j2) * HW] = acc2[j2];
}

extern "C" void kernel_launch(void* const* d_in, const int* in_sizes, int n_in,
                              void* d_out, int out_size, void* d_ws, size_t ws_size,
                              hipStream_t stream) {
  const float* z    = (const float*)d_in[0];
  const float* cond = (const float*)d_in[1];
  const float* Wq = (const float*)d_in[2];  const float* bq = (const float*)d_in[3];
  const float* Aq = (const float*)d_in[4];  const float* Bq = (const float*)d_in[5];
  const float* Wk = (const float*)d_in[6];  const float* bk = (const float*)d_in[7];
  const float* Ak = (const float*)d_in[8];  const float* Bk = (const float*)d_in[9];
  const float* Wv = (const float*)d_in[10]; const float* bv = (const float*)d_in[11];
  const float* Av = (const float*)d_in[12]; const float* Bv = (const float*)d_in[13];
  const float* Wo = (const float*)d_in[14]; const float* bo = (const float*)d_in[15];
  const float* Ao = (const float*)d_in[16]; const float* Bo = (const float*)d_in[17];
  float* ws  = (float*)d_ws;
  float* out = (float*)d_out;

  prep_weights<<<416, 256, 0, stream>>>(Wq, Aq, Bq, Wk, Ak, Bk, Wv, Av, Bv, Wo, Ao, Bo, ws);
  kvproj3<<<dim3(154, 2), 64, 0, stream>>>(cond, ws + OFF_WK, ws + OFF_WV, bk, bv,
                                           ws + OFF_K, ws + OFF_V);
  megattn<<<dim3(32, 16), 256, 0, stream>>>(z, ws + OFF_WQ, bq, ws + OFF_K, ws + OFF_V,
                                            ws + OFF_WO, bo, out);
}

// Round 5
// 147.230 us; speedup vs baseline: 1.4522x; 1.4522x over previous
//
#include <hip/hip_runtime.h>

// CrossAttention with LoRA (folded). B=16, C=64, hw=4096, L=77, COND=768, HEADS=8, dh=8.
// Round 6: kvproj4 — 616 blocks (308 row-tiles x 2 kv), 256 thr, wave = K-quarter.
// x staged in LDS (coalesced float4), weights = coalesced vector dwords, x reads =
// wave-uniform ds_read_b128 broadcasts, 4-way LDS reduction. No scalar-load chains,
// 2.4 waves/SIMD. kvproj3's failure: 0.3 waves/SIMD + serial s_load chain (VALUBusy 3%).
// Pipeline: prep_weights -> kvproj4 -> megattn  (3 launches).

#define HW   4096
#define CHN  64
#define LSEQ 77
#define CD   768
#define NB   16

// workspace float offsets
#define OFF_WQ 0
#define OFF_WK 4096
#define OFF_WV 53248
#define OFF_WO 102400
#define OFF_K  106496
#define OFF_V  185344

#define QF 0.51011784563163f  // SCALE * log2(e) = 8^-0.5 * 1.442695...

__global__ __launch_bounds__(256) void prep_weights(
    const float* __restrict__ Wq, const float* __restrict__ Aq, const float* __restrict__ Bq,
    const float* __restrict__ Wk, const float* __restrict__ Ak, const float* __restrict__ Bk,
    const float* __restrict__ Wv, const float* __restrict__ Av, const float* __restrict__ Bv,
    const float* __restrict__ Wo, const float* __restrict__ Ao, const float* __restrict__ Bo,
    float* __restrict__ ws) {
  int idx = blockIdx.x * 256 + threadIdx.x;   // 416*256 = 106496 exact
  const float *W, *A, *Bm;
  float* out;
  int in_d, local;
  float scale = 1.0f;
  if (idx < 4096)        { W = Wq; A = Aq; Bm = Bq; out = ws + OFF_WQ; in_d = 64;  local = idx; scale = QF; }
  else if (idx < 53248)  { W = Wk; A = Ak; Bm = Bk; out = ws + OFF_WK; in_d = 768; local = idx - 4096; }
  else if (idx < 102400) { W = Wv; A = Av; Bm = Bv; out = ws + OFF_WV; in_d = 768; local = idx - 53248; }
  else                   { W = Wo; A = Ao; Bm = Bo; out = ws + OFF_WO; in_d = 64;  local = idx - 102400; }
  int co = local & 63;
  int c  = local >> 6;
  float val = W[co * in_d + c];
  #pragma unroll
  for (int r = 0; r < 8; r++) val += Bm[co * 8 + r] * A[r * in_d + c];
  out[local] = val * scale;   // local == c*64+co : W_eff^T [in][out]
}

// K/V projection: grid (308, 2 kv), block 256 = 4 waves. Tile = 4 rows x 64 co.
// Wave q owns K-quarter [q*192, q*192+192). LDS: x[4][768] staged coalesced; x reads
// are wave-uniform broadcasts; weight reads coalesced 256B; 4-way reduce via LDS.
__global__ __launch_bounds__(256) void kvproj4(
    const float* __restrict__ cond,  // [1232][768]
    const float* __restrict__ wkT,   // [768][64]
    const float* __restrict__ wvT,
    const float* __restrict__ bk, const float* __restrict__ bv,
    float* __restrict__ kbuf,        // [1232][64]
    float* __restrict__ vbuf) {
  __shared__ float xs[4 * CD];       // 12KB
  __shared__ float red[4][4][64];    // 4KB [quarter][row][co]
  int kv = blockIdx.y;
  int r0 = blockIdx.x * 4;           // 308*4 = 1232 exact
  int t  = threadIdx.x;
  int co = t & 63;
  int q  = __builtin_amdgcn_readfirstlane(t >> 6);   // wave-uniform K-quarter

  {
    const float4* src = (const float4*)(cond + r0 * CD);
    float4* dst = (float4*)xs;
    #pragma unroll
    for (int i = 0; i < 3; i++) dst[t + 256 * i] = src[t + 256 * i];  // 768 float4 exact
  }
  __syncthreads();

  const float* wT = (kv ? wvT : wkT) + q * 192 * 64 + co;
  const float4* xs4 = (const float4*)xs;
  float acc0 = 0.f, acc1 = 0.f, acc2 = 0.f, acc3 = 0.f;
  #pragma unroll 4
  for (int c4 = 0; c4 < 48; c4++) {
    float w0 = wT[(4 * c4 + 0) * 64];
    float w1 = wT[(4 * c4 + 1) * 64];
    float w2 = wT[(4 * c4 + 2) * 64];
    float w3 = wT[(4 * c4 + 3) * 64];
    float4 x0 = xs4[0 * 192 + q * 48 + c4];   // wave-uniform -> LDS broadcast
    float4 x1 = xs4[1 * 192 + q * 48 + c4];
    float4 x2 = xs4[2 * 192 + q * 48 + c4];
    float4 x3 = xs4[3 * 192 + q * 48 + c4];
    acc0 = fmaf(x0.x, w0, acc0); acc0 = fmaf(x0.y, w1, acc0);
    acc0 = fmaf(x0.z, w2, acc0); acc0 = fmaf(x0.w, w3, acc0);
    acc1 = fmaf(x1.x, w0, acc1); acc1 = fmaf(x1.y, w1, acc1);
    acc1 = fmaf(x1.z, w2, acc1); acc1 = fmaf(x1.w, w3, acc1);
    acc2 = fmaf(x2.x, w0, acc2); acc2 = fmaf(x2.y, w1, acc2);
    acc2 = fmaf(x2.z, w2, acc2); acc2 = fmaf(x2.w, w3, acc2);
    acc3 = fmaf(x3.x, w0, acc3); acc3 = fmaf(x3.y, w1, acc3);
    acc3 = fmaf(x3.z, w2, acc3); acc3 = fmaf(x3.w, w3, acc3);
  }
  red[q][0][co] = acc0;
  red[q][1][co] = acc1;
  red[q][2][co] = acc2;
  red[q][3][co] = acc3;
  __syncthreads();

  int lr = t >> 6;   // reuse wave id as row id: 4 rows x 64 co = 256 outputs exact
  float val = (kv ? bv : bk)[co]
            + red[0][lr][co] + red[1][lr][co] + red[2][lr][co] + red[3][lr][co];
  (kv ? vbuf : kbuf)[(r0 + lr) * 64 + co] = val;
}

// Fused q-proj + attention + o-proj (round-0 geometry: 256 threads, 4 px/thread).
// grid (32 ptiles of 128, 16 b), block 256. h = t>>5, pl = t&31, 4 pixels/thread.
// qT never materialized; ao round-trips through LDS (stride-65 padding, 2-way conflict = free).
// Logits bounded => single-pass softmax with exp2 (wqT pre-scaled by SCALE*log2e).
__global__ __launch_bounds__(256, 2) void megattn(
    const float* __restrict__ z,     // [16][64][4096]
    const float* __restrict__ wqT,   // [64][64] (pre-scaled by QF)
    const float* __restrict__ bq,
    const float* __restrict__ kbuf,  // [16][77][64]
    const float* __restrict__ vbuf,
    const float* __restrict__ woT,   // [64][64]
    const float* __restrict__ bo,
    float* __restrict__ out) {       // [16][64][4096]
  __shared__ float smem[LSEQ * 64 * 2];   // 9856 floats: k|v ; later reused as ao[128][65]
  int b  = blockIdx.y;
  int p0 = blockIdx.x * 128;
  int t  = threadIdx.x;
  int h  = t >> 5;
  int pl = t & 31;

  float* ks = smem;
  float* vs = smem + LSEQ * 64;
  {
    const float4* ksrc = (const float4*)(kbuf + b * LSEQ * 64);
    const float4* vsrc = (const float4*)(vbuf + b * LSEQ * 64);
    float4* kd = (float4*)ks;
    float4* vd = (float4*)vs;
    for (int i = t; i < LSEQ * 16; i += 256) { kd[i] = ksrc[i]; vd[i] = vsrc[i]; }
  }

  // ---- Q phase: q[p][8h..8h+7] for p = p0 + pl + 32*i, i<4 (runs before the barrier) ----
  float qr[4][8];
  {
    const float4 b0 = *(const float4*)(bq + 8 * h);
    const float4 b1 = *(const float4*)(bq + 8 * h + 4);
    #pragma unroll
    for (int i = 0; i < 4; i++) {
      qr[i][0] = b0.x * QF; qr[i][1] = b0.y * QF; qr[i][2] = b0.z * QF; qr[i][3] = b0.w * QF;
      qr[i][4] = b1.x * QF; qr[i][5] = b1.y * QF; qr[i][6] = b1.z * QF; qr[i][7] = b1.w * QF;
    }
  }
  const float* zb = z + b * (CHN * HW) + p0 + pl;
  #pragma unroll 4
  for (int c = 0; c < 64; c++) {
    float4 w0 = *(const float4*)(wqT + c * 64 + 8 * h);
    float4 w1 = *(const float4*)(wqT + c * 64 + 8 * h + 4);
    float zv[4];
    #pragma unroll
    for (int i = 0; i < 4; i++) zv[i] = zb[c * HW + 32 * i];
    #pragma unroll
    for (int i = 0; i < 4; i++) {
      qr[i][0] = fmaf(zv[i], w0.x, qr[i][0]);
      qr[i][1] = fmaf(zv[i], w0.y, qr[i][1]);
      qr[i][2] = fmaf(zv[i], w0.z, qr[i][2]);
      qr[i][3] = fmaf(zv[i], w0.w, qr[i][3]);
      qr[i][4] = fmaf(zv[i], w1.x, qr[i][4]);
      qr[i][5] = fmaf(zv[i], w1.y, qr[i][5]);
      qr[i][6] = fmaf(zv[i], w1.z, qr[i][6]);
      qr[i][7] = fmaf(zv[i], w1.w, qr[i][7]);
    }
  }
  __syncthreads();

  // ---- Attention phase ----
  float acc[4][8];
  float li[4];
  #pragma unroll
  for (int i = 0; i < 4; i++) {
    li[i] = 0.f;
    #pragma unroll
    for (int d = 0; d < 8; d++) acc[i][d] = 0.f;
  }
  #pragma unroll 2
  for (int j = 0; j < LSEQ; j++) {
    float4 k0 = *(const float4*)(ks + j * 64 + 8 * h);
    float4 k1 = *(const float4*)(ks + j * 64 + 8 * h + 4);
    float4 v0 = *(const float4*)(vs + j * 64 + 8 * h);
    float4 v1 = *(const float4*)(vs + j * 64 + 8 * h + 4);
    #pragma unroll
    for (int i = 0; i < 4; i++) {
      float s = qr[i][0] * k0.x;
      s = fmaf(qr[i][1], k0.y, s);
      s = fmaf(qr[i][2], k0.z, s);
      s = fmaf(qr[i][3], k0.w, s);
      s = fmaf(qr[i][4], k1.x, s);
      s = fmaf(qr[i][5], k1.y, s);
      s = fmaf(qr[i][6], k1.z, s);
      s = fmaf(qr[i][7], k1.w, s);
      float e = __builtin_amdgcn_exp2f(s);
      li[i] += e;
      acc[i][0] = fmaf(e, v0.x, acc[i][0]);
      acc[i][1] = fmaf(e, v0.y, acc[i][1]);
      acc[i][2] = fmaf(e, v0.z, acc[i][2]);
      acc[i][3] = fmaf(e, v0.w, acc[i][3]);
      acc[i][4] = fmaf(e, v1.x, acc[i][4]);
      acc[i][5] = fmaf(e, v1.y, acc[i][5]);
      acc[i][6] = fmaf(e, v1.z, acc[i][6]);
      acc[i][7] = fmaf(e, v1.w, acc[i][7]);
    }
  }
  __syncthreads();   // all k/v reads done; smem reusable

  // ---- ao -> LDS, layout [128][65] (stride 65: 2 lanes/bank = free) ----
  float* ao = smem;
  #pragma unroll
  for (int i = 0; i < 4; i++) {
    float inv = 1.0f / li[i];
    int p = pl + 32 * i;
    #pragma unroll
    for (int d = 0; d < 8; d++) ao[p * 65 + 8 * h + d] = acc[i][d] * inv;
  }
  __syncthreads();

  // ---- O phase: out[p][co] = ao[p] . woT[:,co] + bo ----
  int q2 = t & 127;
  int chalf = __builtin_amdgcn_readfirstlane((t >> 7) & 1);  // wave-uniform -> scalar weight loads
  float acc2[32];
  #pragma unroll
  for (int j2 = 0; j2 < 32; j2++) acc2[j2] = bo[chalf * 32 + j2];
  const float* aor = ao + q2 * 65;
  #pragma unroll 4
  for (int c = 0; c < 64; c++) {
    float xv = aor[c];
    const float* wr = woT + c * 64 + chalf * 32;
    #pragma unroll
    for (int j2 = 0; j2 < 32; j2++) acc2[j2] = fmaf(xv, wr[j2], acc2[j2]);
  }
  float* ob = out + b * (CHN * HW) + p0 + q2;
  #pragma unroll
  for (int j2 = 0; j2 < 32; j2++) ob[(chalf * 32 + j2) * HW] = acc2[j2];
}

extern "C" void kernel_launch(void* const* d_in, const int* in_sizes, int n_in,
                              void* d_out, int out_size, void* d_ws, size_t ws_size,
                              hipStream_t stream) {
  const float* z    = (const float*)d_in[0];
  const float* cond = (const float*)d_in[1];
  const float* Wq = (const float*)d_in[2];  const float* bq = (const float*)d_in[3];
  const float* Aq = (const float*)d_in[4];  const float* Bq = (const float*)d_in[5];
  const float* Wk = (const float*)d_in[6];  const float* bk = (const float*)d_in[7];
  const float* Ak = (const float*)d_in[8];  const float* Bk = (const float*)d_in[9];
  const float* Wv = (const float*)d_in[10]; const float* bv = (const float*)d_in[11];
  const float* Av = (const float*)d_in[12]; const float* Bv = (const float*)d_in[13];
  const float* Wo = (const float*)d_in[14]; const float* bo = (const float*)d_in[15];
  const float* Ao = (const float*)d_in[16]; const float* Bo = (const float*)d_in[17];
  float* ws  = (float*)d_ws;
  float* out = (float*)d_out;

  prep_weights<<<416, 256, 0, stream>>>(Wq, Aq, Bq, Wk, Ak, Bk, Wv, Av, Bv, Wo, Ao, Bo, ws);
  kvproj4<<<dim3(308, 2), 256, 0, stream>>>(cond, ws + OFF_WK, ws + OFF_WV, bk, bv,
                                            ws + OFF_K, ws + OFF_V);
  megattn<<<dim3(32, 16), 256, 0, stream>>>(z, ws + OFF_WQ, bq, ws + OFF_K, ws + OFF_V,
                                            ws + OFF_WO, bo, out);
}